// Round 1
// baseline (180.352 us; speedup 1.0000x reference)
//
#include <hip/hip_runtime.h>

#define NQ 12
#define NLAYERS 8
#define BATCH 1024

__device__ __forceinline__ float bperm(int addr, float v) {
    return __int_as_float(__builtin_amdgcn_ds_bpermute(addr, __float_as_int(v)));
}

// Amplitude index = (lane << 6) | j.  Wire w occupies bit (11-w) of the index:
//   wires 0..5  -> lane bits 5..0
//   wires 6..11 -> local bits 5..0 of j

template<int W>
__device__ __forceinline__ void rx_gate(float (&re)[64], float (&im)[64],
                                        float hc, float hs, int lane) {
    if constexpr (W >= 6) {
        constexpr int bm = 1 << (11 - W);
        #pragma unroll
        for (int j = 0; j < 64; ++j) {
            if (j & bm) continue;
            const int j2 = j | bm;
            float r0 = re[j], i0 = im[j], r1 = re[j2], i1 = im[j2];
            re[j]  = hc * r0 + hs * i1;
            im[j]  = hc * i0 - hs * r1;
            re[j2] = hc * r1 + hs * i0;
            im[j2] = hc * i1 - hs * r0;
        }
    } else {
        constexpr int lm = 1 << (5 - W);
        #pragma unroll
        for (int j = 0; j < 64; ++j) {
            float pr = __shfl_xor(re[j], lm, 64);
            float pi = __shfl_xor(im[j], lm, 64);
            float r = re[j], i = im[j];
            re[j] = hc * r + hs * pi;   // works for both sides of the pair
            im[j] = hc * i - hs * pr;
        }
    }
}

template<int W>
__device__ __forceinline__ void rz_gate(float (&re)[64], float (&im)[64],
                                        float hc, float hs, int lane) {
    if constexpr (W >= 6) {
        constexpr int bm = 1 << (11 - W);
        #pragma unroll
        for (int j = 0; j < 64; ++j) {
            float r = re[j], i = im[j];
            if (j & bm) { re[j] = hc * r - hs * i; im[j] = hc * i + hs * r; }
            else        { re[j] = hc * r + hs * i; im[j] = hc * i - hs * r; }
        }
    } else {
        float sg = ((lane >> (5 - W)) & 1) ? -hs : hs;
        #pragma unroll
        for (int j = 0; j < 64; ++j) {
            float r = re[j], i = im[j];
            re[j] = hc * r + sg * i;
            im[j] = hc * i - sg * r;
        }
    }
}

template<int C>   // control wire C, target wire C+1
__device__ __forceinline__ void cnot_gate(float (&re)[64], float (&im)[64], int lane) {
    if constexpr (C <= 4) {
        // ctrl = lane bit (5-C), tgt = lane bit (4-C): cross-lane pull
        constexpr int tm = 1 << (4 - C);
        const int ctrl = (lane >> (5 - C)) & 1;
        const int addr = (ctrl ? (lane ^ tm) : lane) << 2;
        #pragma unroll
        for (int j = 0; j < 64; ++j) {
            re[j] = bperm(addr, re[j]);
            im[j] = bperm(addr, im[j]);
        }
    } else if constexpr (C == 5) {
        // ctrl = lane bit 0, tgt = local bit 5
        const bool p = (lane & 1) != 0;
        #pragma unroll
        for (int j = 0; j < 32; ++j) {
            float a = re[j], b = re[j | 32];
            re[j]      = p ? b : a;
            re[j | 32] = p ? a : b;
            float c2 = im[j], d = im[j | 32];
            im[j]      = p ? d : c2;
            im[j | 32] = p ? c2 : d;
        }
    } else {
        // both local: pure compile-time register swap (free)
        constexpr int cm = 1 << (11 - C);
        constexpr int tm = 1 << (10 - C);
        #pragma unroll
        for (int j = 0; j < 64; ++j) {
            if ((j & cm) && !(j & tm)) {
                const int j2 = j | tm;
                float t = re[j]; re[j] = re[j2]; re[j2] = t;
                t = im[j]; im[j] = im[j2]; im[j2] = t;
            }
        }
    }
}

__global__ __launch_bounds__(256, 1) void qnn_kernel(
    const float* __restrict__ x, const float* __restrict__ P,
    const float* __restrict__ Wm, float* __restrict__ out)
{
    const int lane = threadIdx.x & 63;
    const int wave = threadIdx.x >> 6;
    const int b = blockIdx.x * 4 + wave;

    float re[64], im[64];
    #pragma unroll
    for (int j = 0; j < 64; ++j) { re[j] = 0.0f; im[j] = 0.0f; }
    if (lane == 0) re[0] = 1.0f;

    // ---- initial RX(x[b][i] * pi) on each wire ----
    #define INIT_RX(i) { float hs, hc; \
        __sincosf(x[b * NQ + i] * 1.5707963267948966f, &hs, &hc); \
        rx_gate<i>(re, im, hc, hs, lane); }
    INIT_RX(0) INIT_RX(1) INIT_RX(2) INIT_RX(3) INIT_RX(4) INIT_RX(5)
    INIT_RX(6) INIT_RX(7) INIT_RX(8) INIT_RX(9) INIT_RX(10) INIT_RX(11)
    #undef INIT_RX

    // ---- 8 layers ----
    #pragma unroll 1
    for (int l = 0; l < NLAYERS; ++l) {
        const float* p = P + l * 2 * NQ;
        cnot_gate<0>(re, im, lane);
        cnot_gate<1>(re, im, lane);
        cnot_gate<2>(re, im, lane);
        cnot_gate<3>(re, im, lane);
        cnot_gate<4>(re, im, lane);
        cnot_gate<5>(re, im, lane);
        cnot_gate<6>(re, im, lane);
        cnot_gate<7>(re, im, lane);
        cnot_gate<8>(re, im, lane);
        cnot_gate<9>(re, im, lane);
        cnot_gate<10>(re, im, lane);
        #define RXRZ(i) { float hs, hc; \
            __sincosf(p[2 * i] * 0.5f, &hs, &hc); \
            rx_gate<i>(re, im, hc, hs, lane); \
            __sincosf(p[2 * i + 1] * 0.5f, &hs, &hc); \
            rz_gate<i>(re, im, hc, hs, lane); }
        RXRZ(0) RXRZ(1) RXRZ(2) RXRZ(3) RXRZ(4) RXRZ(5)
        RXRZ(6) RXRZ(7) RXRZ(8) RXRZ(9) RXRZ(10) RXRZ(11)
        #undef RXRZ
    }

    // ---- PauliZ expvals ----
    float ptot = 0.0f;
    float zl[6] = {0.f, 0.f, 0.f, 0.f, 0.f, 0.f};
    #pragma unroll
    for (int j = 0; j < 64; ++j) {
        float pr = re[j] * re[j] + im[j] * im[j];
        ptot += pr;
        zl[0] += (j & 32) ? -pr : pr;   // wire 6
        zl[1] += (j & 16) ? -pr : pr;   // wire 7
        zl[2] += (j &  8) ? -pr : pr;   // wire 8
        zl[3] += (j &  4) ? -pr : pr;   // wire 9
        zl[4] += (j &  2) ? -pr : pr;   // wire 10
        zl[5] += (j &  1) ? -pr : pr;   // wire 11
    }

    float z[12];
    #pragma unroll
    for (int w = 0; w < 6; ++w)
        z[w] = ((lane >> (5 - w)) & 1) ? -ptot : ptot;
    #pragma unroll
    for (int w = 0; w < 6; ++w) z[6 + w] = zl[w];

    #pragma unroll
    for (int m = 1; m < 64; m <<= 1) {
        #pragma unroll
        for (int w = 0; w < 12; ++w)
            z[w] += __shfl_xor(z[w], m, 64);
    }

    // ---- relu(z @ W) summed over columns ----
    float acc = 0.0f;
    #pragma unroll
    for (int c = 0; c < 12; ++c) {
        float t = 0.0f;
        #pragma unroll
        for (int w = 0; w < 12; ++w)
            t = fmaf(z[w], Wm[w * 12 + c], t);
        acc += fmaxf(t, 0.0f);
    }
    if (lane == 0) out[b] = acc;
}

extern "C" void kernel_launch(void* const* d_in, const int* in_sizes, int n_in,
                              void* d_out, int out_size, void* d_ws, size_t ws_size,
                              hipStream_t stream) {
    const float* x  = (const float*)d_in[0];
    const float* P  = (const float*)d_in[1];
    const float* Wm = (const float*)d_in[2];
    float* out = (float*)d_out;
    qnn_kernel<<<BATCH / 4, 256, 0, stream>>>(x, P, Wm, out);
}

// Round 2
// 130.739 us; speedup vs baseline: 1.3795x; 1.3795x over previous
//
#include <hip/hip_runtime.h>

#define NQ 12
#define NLAYERS 8
#define BATCH 1024

// ---------------------------------------------------------------------------
// CNOT folding: physical state is never permuted. Invariant: phys[p] = psi[L p]
// with L linear over GF(2). The CNOT ladder (c=0..10: wire_{c+1} ^= wire_c)
// makes L <- P*L where P = lower-triangular all-ones (prefix-xor). After layer
// l, L = P^l. P^{-1} = I + N (N = shift to next wire), so P^{-l} = (I+N)^l.
//   RX(w) partner mask:  M_w(l) = P^{-l} e_w = { w+j : C(l,j) odd }
//   RZ(w) sign row:      R_w(l) = row w of P^l = { w-j : C(l+j-1,j) odd }
// Physical index p = (wv<<11)|(lane<<5)|j :
//   wire0 = wave bit; wires1..6 = lane bits 5..0; wires7..11 = j bits 4..0.
// ---------------------------------------------------------------------------

constexpr bool codd(int n, int k){ return k==0 || (n>=0 && (k & ~n)==0); }   // C(n,k) odd (Lucas)
constexpr int Mwire(int l, int w){ int m=0; for(int j=0; w+j<=11; ++j) if(codd(l,j)) m |= 1<<(w+j); return m; }
constexpr int Rwire(int l, int w){ int m=0; for(int j=0; j<=w;    ++j) if(codd(l+j-1,j)) m |= 1<<(w-j); return m; }
constexpr int laneOf(int wm){ int r=0; for(int w=1;w<=6;++w)  if((wm>>w)&1) r |= 1<<(6-w);  return r; }
constexpr int jOf(int wm){    int r=0; for(int w=7;w<=11;++w) if((wm>>w)&1) r |= 1<<(11-w); return r; }
constexpr int wvOf(int wm){ return wm & 1; }
constexpr int hbit(int m){ int h=0; while(m>>(h+1)) ++h; return 1<<h; }

__device__ __forceinline__ float bperm(int addr, float v){
    return __int_as_float(__builtin_amdgcn_ds_bpermute(addr, __float_as_int(v)));
}

// RX with cross-lane partner (lane^LM, j^JM), same wave.
template<int LM, int JM>
__device__ __forceinline__ void rx_cross(float (&re)[32], float (&im)[32], float hc, float hs, int lane){
    const int addr = ((lane ^ LM) & 63) << 2;
    if constexpr (JM == 0){
        #pragma unroll
        for (int j=0;j<32;++j){
            float r=re[j], i=im[j];
            float pr=bperm(addr,r), pi=bperm(addr,i);
            re[j]=fmaf(hc,r, hs*pi);
            im[j]=fmaf(hc,i,-hs*pr);
        }
    } else {
        constexpr int HB = hbit(JM);
        #pragma unroll
        for (int j=0;j<32;++j){
            if (j & HB) continue;
            const int j2 = j ^ JM;
            float r=re[j], i=im[j], r2=re[j2], i2=im[j2];
            float pr =bperm(addr,r2), pi =bperm(addr,i2);   // partner of (lane,j)
            float pr2=bperm(addr,r ), pi2=bperm(addr,i );   // partner of (lane,j2)
            re[j ]=fmaf(hc,r ,  hs*pi );
            im[j ]=fmaf(hc,i , -hs*pr );
            re[j2]=fmaf(hc,r2,  hs*pi2);
            im[j2]=fmaf(hc,i2, -hs*pr2);
        }
    }
}

// RX fully thread-local (partner j^JM in own registers).
template<int JM>
__device__ __forceinline__ void rx_local(float (&re)[32], float (&im)[32], float hc, float hs){
    constexpr int HB = hbit(JM);
    #pragma unroll
    for (int j=0;j<32;++j){
        if (j & HB) continue;
        const int j2 = j ^ JM;
        float r=re[j], i=im[j], r2=re[j2], i2=im[j2];
        re[j ]=fmaf(hc,r ,  hs*i2);
        im[j ]=fmaf(hc,i , -hs*r2);
        re[j2]=fmaf(hc,r2,  hs*i );
        im[j2]=fmaf(hc,i2, -hs*r );
    }
}

// RX whose partner is in the OTHER wave: full-state exchange through LDS.
// LDS plane layout: [wave][j][lane] -> bank = lane%32, conflict-free b32.
template<int LM, int JM>
__device__ __forceinline__ void rx_wave(float (&re)[32], float (&im)[32], float hc, float hs,
                                        int lane, int wv, float* ldsRe, float* ldsIm){
    float* wrRe = ldsRe + (wv*32)*64 + lane;
    float* wrIm = ldsIm + (wv*32)*64 + lane;
    #pragma unroll
    for (int j=0;j<32;++j){ wrRe[j*64] = re[j]; wrIm[j*64] = im[j]; }
    __syncthreads();
    const int pl = (lane ^ LM) & 63;
    const float* rdRe = ldsRe + ((wv^1)*32)*64 + pl;
    const float* rdIm = ldsIm + ((wv^1)*32)*64 + pl;
    #pragma unroll
    for (int j=0;j<32;++j){
        float pr = rdRe[(j^JM)*64], pi = rdIm[(j^JM)*64];
        re[j] = fmaf(hc, re[j],  hs*pi);
        im[j] = fmaf(hc, im[j], -hs*pr);
    }
    __syncthreads();
}

// RZ: diagonal, sign = parity(R & p). RW is the wire-space row mask.
template<int RW>
__device__ __forceinline__ void rz_gate(float (&re)[32], float (&im)[32], float hc, float hs, int lane, int wv){
    constexpr int LM = laneOf(RW);
    constexpr int JM = jOf(RW);
    int par = __popc(lane & LM) & 1;
    if constexpr (wvOf(RW)) par ^= wv;
    const float hsp = par ? -hs : hs;
    #pragma unroll
    for (int j=0;j<32;++j){
        float r=re[j], i=im[j];
        if (__builtin_popcount(j & JM) & 1){   // constant-folds after unroll
            re[j]=fmaf(hc,r, -hsp*i);
            im[j]=fmaf(hc,i,  hsp*r);
        } else {
            re[j]=fmaf(hc,r,  hsp*i);
            im[j]=fmaf(hc,i, -hsp*r);
        }
    }
}

template<int L, int W>
__device__ __forceinline__ void wire_gates(float (&re)[32], float (&im)[32], const float* __restrict__ p,
                                           int lane, int wv, float* ldsRe, float* ldsIm){
    float hs, hc;
    __sincosf(p[2*W]*0.5f, &hs, &hc);
    constexpr int M  = Mwire(L, W);
    constexpr int LM = laneOf(M);
    constexpr int JM = jOf(M);
    if constexpr (wvOf(M))       rx_wave<LM,JM>(re,im,hc,hs,lane,wv,ldsRe,ldsIm);
    else if constexpr (LM != 0)  rx_cross<LM,JM>(re,im,hc,hs,lane);
    else                         rx_local<JM>(re,im,hc,hs);
    __sincosf(p[2*W+1]*0.5f, &hs, &hc);
    rz_gate<Rwire(L,W)>(re,im,hc,hs,lane,wv);
    if constexpr (W+1 < NQ) wire_gates<L, W+1>(re,im,p,lane,wv,ldsRe,ldsIm);
}

template<int W>
__device__ __forceinline__ void init_rx(float (&re)[32], float (&im)[32], const float* __restrict__ xb,
                                        int lane, int wv, float* ldsRe, float* ldsIm){
    float hs, hc;
    __sincosf(xb[W]*1.5707963267948966f, &hs, &hc);
    if constexpr (W == 0)      rx_wave<0,0>(re,im,hc,hs,lane,wv,ldsRe,ldsIm);
    else if constexpr (W <= 6) rx_cross<(1<<(6-W)),0>(re,im,hc,hs,lane);
    else                       rx_local<(1<<(11-W))>(re,im,hc,hs);
    if constexpr (W+1 < NQ) init_rx<W+1>(re,im,xb,lane,wv,ldsRe,ldsIm);
}

template<int L>
__device__ __forceinline__ void run_layers(float (&re)[32], float (&im)[32], const float* __restrict__ P,
                                           int lane, int wv, float* ldsRe, float* ldsIm){
    wire_gates<L,0>(re,im, P + (L-1)*2*NQ, lane, wv, ldsRe, ldsIm);
    if constexpr (L < NLAYERS) run_layers<L+1>(re,im,P,lane,wv,ldsRe,ldsIm);
}

__global__ __launch_bounds__(128, 2) void qnn_kernel(const float* __restrict__ x,
                                                     const float* __restrict__ P,
                                                     const float* __restrict__ Wm,
                                                     float* __restrict__ out)
{
    __shared__ float ldsRe[2*32*64];
    __shared__ float ldsIm[2*32*64];
    const int lane = threadIdx.x & 63;
    const int wv   = threadIdx.x >> 6;
    const int b    = blockIdx.x;

    float re[32], im[32];
    #pragma unroll
    for (int j=0;j<32;++j){ re[j]=0.f; im[j]=0.f; }
    if (lane==0 && wv==0) re[0] = 1.0f;

    init_rx<0>(re, im, x + b*NQ, lane, wv, ldsRe, ldsIm);
    run_layers<1>(re, im, P, lane, wv, ldsRe, ldsIm);

    // ---- PauliZ expvals under final L = P^8: row_w = e_w ^ e_{w-8} ----
    float s0=0.f, sj0=0.f, sj1=0.f, sj2=0.f, sj3=0.f, sj4=0.f;
    #pragma unroll
    for (int j=0;j<32;++j){
        float pr = fmaf(re[j],re[j], im[j]*im[j]);
        s0  += pr;
        sj4 += (j&16)? -pr : pr;   // j bit4 (wire 7)
        sj3 += (j& 8)? -pr : pr;   // j bit3 (wire 8 local part)
        sj2 += (j& 4)? -pr : pr;   // j bit2 (wire 9 local part)
        sj1 += (j& 2)? -pr : pr;   // j bit1 (wire 10 local part)
        sj0 += (j& 1)? -pr : pr;   // j bit0 (wire 11 local part)
    }
    float z[12];
    z[0] = wv ? -s0 : s0;
    #pragma unroll
    for (int w=1; w<=6; ++w) z[w] = ((lane >> (6-w)) & 1) ? -s0 : s0;
    z[7]  = sj4;
    z[8]  = wv            ? -sj3 : sj3;   // ^ wire0 (wv)
    z[9]  = ((lane>>5)&1) ? -sj2 : sj2;   // ^ wire1 (lane bit5)
    z[10] = ((lane>>4)&1) ? -sj1 : sj1;   // ^ wire2 (lane bit4)
    z[11] = ((lane>>3)&1) ? -sj0 : sj0;   // ^ wire3 (lane bit3)

    #pragma unroll
    for (int m=1; m<64; m<<=1){
        #pragma unroll
        for (int w=0; w<12; ++w) z[w] += __shfl_xor(z[w], m, 64);
    }

    // cross-wave combine + linear head (LDS is idle since last exchange)
    if (lane == 0){
        #pragma unroll
        for (int w=0; w<12; ++w) ldsRe[wv*12 + w] = z[w];
    }
    __syncthreads();
    if (wv == 0){
        float t = 0.f;
        if (lane < 12){
            #pragma unroll
            for (int w=0; w<12; ++w){
                float zz = ldsRe[w] + ldsRe[12 + w];
                t = fmaf(zz, Wm[w*12 + lane], t);
            }
            t = fmaxf(t, 0.f);
        }
        #pragma unroll
        for (int m=1; m<16; m<<=1) t += __shfl_xor(t, m, 64);
        if (lane == 0) out[b] = t;
    }
}

extern "C" void kernel_launch(void* const* d_in, const int* in_sizes, int n_in,
                              void* d_out, int out_size, void* d_ws, size_t ws_size,
                              hipStream_t stream) {
    const float* x  = (const float*)d_in[0];
    const float* P  = (const float*)d_in[1];
    const float* Wm = (const float*)d_in[2];
    float* out = (float*)d_out;
    qnn_kernel<<<BATCH, 128, 0, stream>>>(x, P, Wm, out);
}